// Round 9
// baseline (784.018 us; speedup 1.0000x reference)
//
#include <hip/hip_runtime.h>
#include <math.h>

#define HH 128
#define HP 64   // u32 pairs per 128-feature row

typedef __attribute__((ext_vector_type(8))) short short8;
typedef __attribute__((ext_vector_type(4))) float float4v;
typedef __attribute__((ext_vector_type(4))) unsigned uint4v;

// ---------- helpers ----------
__device__ __forceinline__ float blo(unsigned w){ return __uint_as_float(w << 16); }
__device__ __forceinline__ float bhi(unsigned w){ return __uint_as_float(w & 0xffff0000u); }
__device__ __forceinline__ unsigned short f2b(float x){
  unsigned u = __float_as_uint(x);
  u += 0x7fffu + ((u >> 16) & 1u);           // RNE to bf16
  return (unsigned short)(u >> 16);
}
__device__ __forceinline__ unsigned pack2(float a, float b){
  return (unsigned)f2b(a) | ((unsigned)f2b(b) << 16);
}
__device__ __forceinline__ float silu_f(float x){ return x / (1.f + __expf(-x)); }

// LDS-only barrier: publishes ds_writes (lgkmcnt) WITHOUT draining vmcnt —
// outstanding atomics/prefetch gathers float across (they have no cross-wave
// readers). Memory-clobber asm on both sides pins IR-level ordering;
// sched_barrier(0) pins the machine scheduler (guide rule #18).
__device__ __forceinline__ void bar_lds()
{
  __builtin_amdgcn_sched_barrier(0);
  asm volatile("s_waitcnt lgkmcnt(0)" ::: "memory");
  __builtin_amdgcn_s_barrier();
  asm volatile("" ::: "memory");
  __builtin_amdgcn_sched_barrier(0);
}

// ---------- 1) fused MFMA precompute ----------
// Output layout of A/B rows is PERMUTED for the edge kernel's dwordx4 gathers:
// pair index jp' = (n>>6)*32 + ((n&15)>>1)*4 + ((n>>4)&3)   [n = feature 0..127]
__global__ __launch_bounds__(256, 2) void precompute_mfma_kernel(
    const float* __restrict__ h,
    const float* __restrict__ We1, const float* __restrict__ be1,
    const float* __restrict__ Wc1, const float* __restrict__ bc1,
    unsigned* __restrict__ A1, unsigned* __restrict__ B1,
    unsigned* __restrict__ Ac, unsigned* __restrict__ Bc, int N)
{
  __shared__ unsigned short hs[2][16 * 136];  // 8.7 KB, stride 136

  const int t = threadIdx.x;
  const int lane = t & 63;
  const int w = t >> 6;
  const int col = lane & 15;
  const int quad = lane >> 4;

  const float* Wsel = (w < 2) ? We1 : Wc1;
  const int kb = (w & 1) * 128;               // row base within weight
  unsigned* outp = (w == 0) ? A1 : (w == 1) ? B1 : (w == 2) ? Ac : Bc;
  const float* biasp = (w == 0) ? be1 : (w == 2) ? bc1 : nullptr;

  uint4v wf[8][4];
  #pragma unroll
  for (int nt = 0; nt < 8; ++nt) {
    const int cn = nt * 16 + col;
    #pragma unroll
    for (int ks = 0; ks < 4; ++ks) {
      unsigned u[4];
      #pragma unroll
      for (int i = 0; i < 4; ++i) {
        const int k0 = kb + ks * 32 + quad * 8 + 2 * i;
        u[i] = pack2(Wsel[(size_t)k0 * 128 + cn], Wsel[(size_t)(k0 + 1) * 128 + cn]);
      }
      wf[nt][ks] = (uint4v){u[0], u[1], u[2], u[3]};
    }
  }
  float bias[8];
  #pragma unroll
  for (int nt = 0; nt < 8; ++nt) bias[nt] = biasp ? biasp[nt * 16 + col] : 0.f;

  const int ntiles = (N + 15) >> 4;
  auto stage = [&](int tl, int b) {
    const int n0s = tl * 16;
    for (int idx = t; idx < 16 * 64; idx += 256) {
      const int row = idx >> 6, jp = idx & 63;
      const int n = min(n0s + row, N - 1);
      float2 hv = ((const float2*)h)[(size_t)n * 64 + jp];
      ((unsigned*)&hs[b][row * 136])[jp] = pack2(hv.x, hv.y);
    }
  };

  int tile = blockIdx.x;
  if (tile < ntiles) stage(tile, 0);
  int buf = 0;
  for (; tile < ntiles; tile += gridDim.x, buf ^= 1) {
    __syncthreads();
    if (tile + (int)gridDim.x < ntiles) stage(tile + gridDim.x, buf ^ 1);

    float4v acc[8] = {{0,0,0,0},{0,0,0,0},{0,0,0,0},{0,0,0,0},
                      {0,0,0,0},{0,0,0,0},{0,0,0,0},{0,0,0,0}};
    #pragma unroll
    for (int ks = 0; ks < 4; ++ks) {
      short8 af = __builtin_bit_cast(short8,
          *(const uint4v*)&hs[buf][col * 136 + ks * 32 + quad * 8]);
      #pragma unroll
      for (int nt = 0; nt < 8; ++nt)
        acc[nt] = __builtin_amdgcn_mfma_f32_16x16x32_bf16(
            af, __builtin_bit_cast(short8, wf[nt][ks]), acc[nt], 0, 0, 0);
    }
    const int n0 = tile * 16;
    #pragma unroll
    for (int nt = 0; nt < 8; ++nt) {
      #pragma unroll
      for (int r = 0; r < 4; ++r) {
        float v = acc[nt][r] + bias[nt];
        float o = __shfl_xor(v, 1, 64);       // neighbor col's value
        const int node = n0 + quad * 4 + r;
        if (!(lane & 1) && node < N)
          outp[(size_t)node * HP + (nt >> 2) * 32 + ((col >> 1) << 2) + (nt & 3)]
              = pack2(v, o);
      }
    }
  }
}

// ---------- 2) MFMA edge kernels: MODE 0 = edge MLP (att -> h_agg), MODE 1 = coord MLP (-> x_agg) ----------
// v8 = v5 envelope (768 blocks, 3/CU, 32-edge tiles, W2Ts in LDS, triple-buffered
//      staging, 1-tile-ahead dwordx4 gathers, 2 barriers/tile, setprio)
//    + LDS-only barriers (lgkmcnt, no vmcnt drain: atomics/gathers float across)
//    + issueG moved to after-B1/after-stage: gather->consume cover grows to
//      phaseB+epilogue+B2+scatter+tailMFMA (~600+ cyc, matches HBM-miss latency).
template<int MODE>
__global__ __launch_bounds__(256, 3) void edge_kernel(
    const unsigned* __restrict__ Apart, const unsigned* __restrict__ Bpart,
    const float* __restrict__ W1,       // (276,128); rows 256..275 = tail
    const float* __restrict__ W2, const float* __restrict__ b2,
    const float* __restrict__ Wv,       // Wa (mode0) or Wc3 (mode1), [128]
    const float* __restrict__ ba_p,     // ba (mode0), unused mode1
    const int* __restrict__ src, const int* __restrict__ dst,
    const float* __restrict__ coords, const float* __restrict__ afeat,
    float* __restrict__ out_agg, int E)
{
  __shared__ unsigned short W2Ts[128 * 136];  // 34 KB bf16, n-major
  __shared__ unsigned short mhl16[32 * 136];  // 8.7 KB bf16: mh[e][k]
  __shared__ unsigned short tailsA[3][32 * 40]; // 7.5 KB A-frags, k>=20 zero pad
  __shared__ float    dif[3][32 * 4];         // dx,dy,dz,rad
  __shared__ int      sl[3][32], dl[3][32];
  __shared__ float    p_lds[4][16];

  const int t = threadIdx.x;
  const int lane = t & 63;
  const int w = t >> 6;
  const int mtile = w >> 1;                   // 0/1 (16-edge half)
  const int nhalf = w & 1;                    // 0/1 (64-col half)
  const int col = lane & 15;
  const int quad = lane >> 4;

  for (int i = t; i < 128 * 128; i += 256) {
    int k = i >> 7, n = i & 127;
    W2Ts[n * 136 + k] = f2b(W2[i]);
  }
  for (int i = t; i < 3 * 32 * 20; i += 256) ((unsigned*)tailsA)[i] = 0u;

  uint4v wtf[4];
  #pragma unroll
  for (int nt = 0; nt < 4; ++nt) {
    const int n = nhalf * 64 + nt * 16 + col;
    unsigned u[4];
    #pragma unroll
    for (int i = 0; i < 4; ++i) {
      const int k0 = quad * 8 + 2 * i;
      float a = (k0     < 20) ? W1[(size_t)(256 + k0    ) * 128 + n] : 0.f;
      float b = (k0 + 1 < 20) ? W1[(size_t)(256 + k0 + 1) * 128 + n] : 0.f;
      u[i] = pack2(a, b);
    }
    wtf[nt] = (uint4v){u[0], u[1], u[2], u[3]};
  }
  float b2reg[4], wvreg[4];
  #pragma unroll
  for (int nt = 0; nt < 4; ++nt) {
    const int n = (nhalf * 4 + nt) * 16 + col;
    b2reg[nt] = b2[n];
    wvreg[nt] = Wv[n];
  }
  const float bav = (MODE == 0) ? ba_p[0] : 0.f;

  // ---- stage per-edge scalars + tail A-frag into buffer b ----
  auto stage = [&](int tl, int b) {
    const int e0s = tl * 32;
    if (t < 32) {
      int eg = e0s + t;
      int s = 0, d = 0;
      if (eg < E) { s = src[eg]; d = dst[eg]; }
      sl[b][t] = s; dl[b][t] = d;
      float dx = coords[s*3+0] - coords[d*3+0];
      float dy = coords[s*3+1] - coords[d*3+1];
      float dz = coords[s*3+2] - coords[d*3+2];
      float rad = sqrtf(dx*dx + dy*dy + dz*dz);
      dif[b][t*4+0] = dx; dif[b][t*4+1] = dy;
      dif[b][t*4+2] = dz; dif[b][t*4+3] = rad;
      unsigned* ta = (unsigned*)&tailsA[b][t * 40];
      ta[0] = pack2(rad, fabsf(dx));
      ta[1] = pack2(fabsf(dy), fabsf(dz));
    }
    if (t < 128) {                            // afeat: 32 edges x 4 float4
      int e = t >> 2, q4 = t & 3;
      int eg = e0s + e;
      float4 v = make_float4(0.f, 0.f, 0.f, 0.f);
      if (eg < E) v = ((const float4*)afeat)[(size_t)eg * 4 + q4];
      unsigned* d4 = (unsigned*)&tailsA[b][e * 40 + 4 + q4 * 4];
      d4[0] = pack2(v.x, v.y);
      d4[1] = pack2(v.z, v.w);
    }
  };

  const int gs = gridDim.x;
  const int ntiles = (E + 31) >> 5;
  const int T0 = blockIdx.x;
  if (T0 < ntiles)      stage(T0, 0);
  if (T0 + gs < ntiles) stage(T0 + gs, 1);
  __syncthreads();                            // W2Ts + pads + stage(0,1) visible (full sync, once)

  // ---- pipelined gathers: dwordx4 per (edge r, A/B) thanks to permuted layout ----
  uint4v wa4[4], wb4[4];
  const int jb4 = nhalf * 32 + ((col >> 1) << 2);
  auto issueG = [&](int b) {
    #pragma unroll
    for (int r = 0; r < 4; ++r) {
      const int e = mtile * 16 + quad * 4 + r;
      wa4[r] = *(const uint4v*)(Apart + (size_t)sl[b][e] * HP + jb4);
      wb4[r] = *(const uint4v*)(Bpart + (size_t)dl[b][e] * HP + jb4);
    }
  };
  if (T0 < ntiles) issueG(0);

  int buf = 0;
  for (int tile = T0; tile < ntiles; tile += gs, buf = (buf == 2) ? 0 : buf + 1) {
    const int e0 = tile * 32;

    __builtin_amdgcn_s_setprio(1);            // compute-dense region begins

    // ---- tail MFMA: acct[nt][r] = tails(e_r) . W1tail[:, n] ----
    float4v acct[4] = {{0,0,0,0},{0,0,0,0},{0,0,0,0},{0,0,0,0}};
    {
      const unsigned short* ap = &tailsA[buf][(mtile * 16 + col) * 40 + quad * 8];
      short8 af = __builtin_bit_cast(short8, *(const uint4v*)ap);
      #pragma unroll
      for (int nt = 0; nt < 4; ++nt)
        acct[nt] = __builtin_amdgcn_mfma_f32_16x16x32_bf16(
            af, __builtin_bit_cast(short8, wtf[nt]), acct[nt], 0, 0, 0);
    }

    // ---- phase A: mh = silu(A[src] + B[dst] + tail) -> mhl16 ----
    const bool hiSel = (col & 1);
    #pragma unroll
    for (int r = 0; r < 4; ++r) {
      const int er_ = mtile * 16 + quad * 4 + r;
      #pragma unroll
      for (int nt = 0; nt < 4; ++nt) {
        unsigned ua = wa4[r][nt], ub = wb4[r][nt];
        float va = hiSel ? bhi(ua) : blo(ua);
        float vb = hiSel ? bhi(ub) : blo(ub);
        float v = va + vb + acct[nt][r];
        mhl16[er_ * 136 + nhalf * 64 + nt * 16 + col] = f2b(silu_f(v));
      }
    }
    bar_lds();                                // B1: mhl published; scatter(t-1) done -> buf reuse safe

    // ---- stage tile t+2 FIRST (its internal vmcnt waits must not zero-cover
    //      the fresh gathers: vmcnt waits oldest-first), THEN issue t+1 gathers ----
    if (tile + 2 * gs < ntiles) stage(tile + 2 * gs, (buf == 0) ? 2 : buf - 1);
    if (tile + gs < ntiles) issueG((buf == 2) ? 0 : buf + 1);

    // ---- phase B: layer 2 via MFMA ----
    float4v acc[4] = {{0,0,0,0},{0,0,0,0},{0,0,0,0},{0,0,0,0}};
    {
      const unsigned short* abase = &mhl16[(mtile * 16 + col) * 136 + quad * 8];
      #pragma unroll
      for (int ks = 0; ks < 4; ++ks) {
        short8 af = __builtin_bit_cast(short8, *(const uint4v*)(abase + ks * 32));
        #pragma unroll
        for (int nt = 0; nt < 4; ++nt) {
          const unsigned short* bp =
              &W2Ts[((nhalf * 4 + nt) * 16 + col) * 136 + ks * 32 + quad * 8];
          short8 bf = __builtin_bit_cast(short8, *(const uint4v*)bp);
          acc[nt] = __builtin_amdgcn_mfma_f32_16x16x32_bf16(af, bf, acc[nt], 0, 0, 0);
        }
      }
    }

    // ---- epilogue: bias + silu + head dot, cross-wave reduce ----
    float p[4] = {0.f, 0.f, 0.f, 0.f};
    #pragma unroll
    for (int nt = 0; nt < 4; ++nt)
      #pragma unroll
      for (int r = 0; r < 4; ++r) {
        float v = silu_f(acc[nt][r] + b2reg[nt]);
        acc[nt][r] = v;
        p[r] += v * wvreg[nt];
      }
    #pragma unroll
    for (int r = 0; r < 4; ++r) {
      #pragma unroll
      for (int off = 1; off < 16; off <<= 1) p[r] += __shfl_xor(p[r], off, 64);
    }
    if (col == 0) {
      #pragma unroll
      for (int r = 0; r < 4; ++r) p_lds[w][quad * 4 + r] = p[r];
    }
    __builtin_amdgcn_s_setprio(0);            // compute-dense region ends
    bar_lds();                                // B2: p_lds + stage(t+2) published

    // ---- scatter (atomics float across future barriers; never drained) ----
    #pragma unroll
    for (int r = 0; r < 4; ++r) {
      const int le = quad * 4 + r;
      const int ei = mtile * 16 + le;
      const int eg = e0 + ei;
      const float pfull = p_lds[w][le] + p_lds[w ^ 1][le];
      if (MODE == 0) {
        if (eg < E) {
          float att = 1.f / (1.f + __expf(-(pfull + bav)));
          int d = dl[buf][ei];
          #pragma unroll
          for (int nt = 0; nt < 4; ++nt) {
            int n = (nhalf * 4 + nt) * 16 + col;
            unsafeAtomicAdd(&out_agg[(size_t)d * HH + n], att * acc[nt][r]);
          }
        }
      } else {
        if (nhalf == 0 && eg < E && col < 3) {
          float rad = dif[buf][ei * 4 + 3];
          float fac = pfull / (rad + 1.f);
          unsafeAtomicAdd(&out_agg[(size_t)dl[buf][ei] * 3 + col],
                          fac * dif[buf][ei * 4 + col]);
        }
      }
    }
    // no trailing barrier: B1 of the next iteration is the rendezvous
  }
}

// ---------- 3) node MLP layer 1 via MFMA ----------
__global__ __launch_bounds__(256, 4) void node_l1_mfma(
    const float* __restrict__ h, const float* __restrict__ h_agg,
    const float* __restrict__ Wn1, const float* __restrict__ bn1,
    unsigned* __restrict__ g, int N)
{
  __shared__ unsigned short xs[2][16 * 264];

  const int t = threadIdx.x;
  const int lane = t & 63;
  const int w = t >> 6;
  const int col = lane & 15;
  const int quad = lane >> 4;
  const int wbase = w * 32;

  uint4v wf[2][8];
  #pragma unroll
  for (int nt = 0; nt < 2; ++nt) {
    const int cn = wbase + nt * 16 + col;
    #pragma unroll
    for (int ks = 0; ks < 8; ++ks) {
      unsigned u[4];
      #pragma unroll
      for (int i = 0; i < 4; ++i) {
        const int k0 = ks * 32 + quad * 8 + 2 * i;
        u[i] = pack2(Wn1[(size_t)k0 * 128 + cn], Wn1[(size_t)(k0 + 1) * 128 + cn]);
      }
      wf[nt][ks] = (uint4v){u[0], u[1], u[2], u[3]};
    }
  }
  float bias[2] = { bn1[wbase + col], bn1[wbase + 16 + col] };

  const int ntiles = (N + 15) >> 4;
  auto stage = [&](int tl, int b) {
    const int n0s = tl * 16;
    for (int idx = t; idx < 16 * 128; idx += 256) {
      const int row = idx >> 7, jp = idx & 127;
      const int n = min(n0s + row, N - 1);
      float2 v = (jp < 64) ? ((const float2*)h)[(size_t)n * 64 + jp]
                           : ((const float2*)h_agg)[(size_t)n * 64 + (jp - 64)];
      ((unsigned*)&xs[b][row * 264])[jp] = pack2(v.x, v.y);
    }
  };

  int tile = blockIdx.x;
  if (tile < ntiles) stage(tile, 0);
  int buf = 0;
  for (; tile < ntiles; tile += gridDim.x, buf ^= 1) {
    __syncthreads();
    if (tile + (int)gridDim.x < ntiles) stage(tile + gridDim.x, buf ^ 1);

    float4v acc[2] = {{0,0,0,0},{0,0,0,0}};
    #pragma unroll
    for (int ks = 0; ks < 8; ++ks) {
      short8 af = __builtin_bit_cast(short8,
          *(const uint4v*)&xs[buf][col * 264 + ks * 32 + quad * 8]);
      acc[0] = __builtin_amdgcn_mfma_f32_16x16x32_bf16(
          af, __builtin_bit_cast(short8, wf[0][ks]), acc[0], 0, 0, 0);
      acc[1] = __builtin_amdgcn_mfma_f32_16x16x32_bf16(
          af, __builtin_bit_cast(short8, wf[1][ks]), acc[1], 0, 0, 0);
    }
    const int n0 = tile * 16;
    #pragma unroll
    for (int nt = 0; nt < 2; ++nt) {
      #pragma unroll
      for (int r = 0; r < 4; ++r) {
        float v = silu_f(acc[nt][r] + bias[nt]);
        float o = __shfl_xor(v, 1, 64);
        const int node = n0 + quad * 4 + r;
        if (!(lane & 1) && node < N)
          g[(size_t)node * HP + ((wbase + nt * 16 + col) >> 1)] = pack2(v, o);
      }
    }
  }
}

// ---------- 4) node MLP layer 2 via MFMA (+ fused coords_out epilogue) ----------
__global__ __launch_bounds__(256, 4) void node_l2_mfma(
    const unsigned* __restrict__ g, const float* __restrict__ h,
    const float* __restrict__ Wn2, const float* __restrict__ bn2,
    float* __restrict__ hout,
    const float* __restrict__ coords, const float* __restrict__ x_agg,
    float* __restrict__ cout, int N)
{
  const int t = threadIdx.x;
  const int lane = t & 63;
  const int w = t >> 6;
  const int col = lane & 15;
  const int quad = lane >> 4;
  const int wbase = w * 32;

  uint4v wf[2][4];
  #pragma unroll
  for (int nt = 0; nt < 2; ++nt) {
    const int cn = wbase + nt * 16 + col;
    #pragma unroll
    for (int ks = 0; ks < 4; ++ks) {
      unsigned u[4];
      #pragma unroll
      for (int i = 0; i < 4; ++i) {
        const int k0 = ks * 32 + quad * 8 + 2 * i;
        u[i] = pack2(Wn2[(size_t)k0 * 128 + cn], Wn2[(size_t)(k0 + 1) * 128 + cn]);
      }
      wf[nt][ks] = (uint4v){u[0], u[1], u[2], u[3]};
    }
  }
  float bias[2] = { bn2[wbase + col], bn2[wbase + 16 + col] };

  const int ntiles = (N + 15) >> 4;
  for (int tile = blockIdx.x; tile < ntiles; tile += gridDim.x) {
    const int n0 = tile * 16;
    const int na = min(n0 + col, N - 1);

    float4v acc[2] = {{0,0,0,0},{0,0,0,0}};
    #pragma unroll
    for (int ks = 0; ks < 4; ++ks) {
      short8 af = __builtin_bit_cast(short8,
          *(const uint4v*)(g + (size_t)na * HP + ks * 16 + quad * 4));
      acc[0] = __builtin_amdgcn_mfma_f32_16x16x32_bf16(
          af, __builtin_bit_cast(short8, wf[0][ks]), acc[0], 0, 0, 0);
      acc[1] = __builtin_amdgcn_mfma_f32_16x16x32_bf16(
          af, __builtin_bit_cast(short8, wf[1][ks]), acc[1], 0, 0, 0);
    }
    #pragma unroll
    for (int nt = 0; nt < 2; ++nt) {
      const int cn = wbase + nt * 16 + col;
      #pragma unroll
      for (int r = 0; r < 4; ++r) {
        const int node = n0 + quad * 4 + r;
        if (node < N) {
          float v = acc[nt][r] + bias[nt] + h[(size_t)node * HH + cn];
          hout[(size_t)node * HH + cn] = v;
        }
      }
    }
  }

  // fused coords_out: cout = coords + x_agg (independent streaming epilogue)
  const int n3 = N * 3;
  for (int i = blockIdx.x * blockDim.x + threadIdx.x; i < n3;
       i += gridDim.x * blockDim.x)
    cout[i] = coords[i] + x_agg[i];
}

extern "C" void kernel_launch(void* const* d_in, const int* in_sizes, int n_in,
                              void* d_out, int out_size, void* d_ws, size_t ws_size,
                              hipStream_t stream)
{
  const float* h      = (const float*)d_in[0];
  const float* coords = (const float*)d_in[1];
  const float* afeat  = (const float*)d_in[2];
  const int*   src    = (const int*)d_in[3];
  const int*   dst    = (const int*)d_in[4];
  const float* We1 = (const float*)d_in[5];
  const float* be1 = (const float*)d_in[6];
  const float* We2 = (const float*)d_in[7];
  const float* be2 = (const float*)d_in[8];
  const float* Wa  = (const float*)d_in[9];
  const float* ba  = (const float*)d_in[10];
  const float* Wn1 = (const float*)d_in[11];
  const float* bn1 = (const float*)d_in[12];
  const float* Wn2 = (const float*)d_in[13];
  const float* bn2 = (const float*)d_in[14];
  const float* Wc1 = (const float*)d_in[15];
  const float* bc1 = (const float*)d_in[16];
  const float* Wc2 = (const float*)d_in[17];
  const float* bc2 = (const float*)d_in[18];
  const float* Wc3 = (const float*)d_in[19];

  const int E = in_sizes[3];
  const int N = in_sizes[0] / HH;

  unsigned* A1 = (unsigned*)d_ws;
  unsigned* B1 = A1 + (size_t)N * HP;
  unsigned* Ac = B1 + (size_t)N * HP;
  unsigned* Bc = Ac + (size_t)N * HP;
  float* h_agg = (float*)(Bc + (size_t)N * HP);
  float* x_agg = h_agg + (size_t)N * HH;
  unsigned* gbuf = A1;                        // reuse after edge kernels finish

  hipMemsetAsync(h_agg, 0, ((size_t)N * HH + (size_t)N * 3) * sizeof(float), stream);

  precompute_mfma_kernel<<<512, 256, 0, stream>>>(h, We1, be1, Wc1, bc1,
                                                  A1, B1, Ac, Bc, N);

  edge_kernel<0><<<768, 256, 0, stream>>>(A1, B1, We1, We2, be2, Wa, ba,
                                          src, dst, coords, afeat, h_agg, E);
  edge_kernel<1><<<768, 256, 0, stream>>>(Ac, Bc, Wc1, Wc2, bc2, Wc3, nullptr,
                                          src, dst, coords, afeat, x_agg, E);

  node_l1_mfma<<<512, 256, 0, stream>>>(h, h_agg, Wn1, bn1, gbuf, N);
  node_l2_mfma<<<1024, 256, 0, stream>>>(gbuf, h, Wn2, bn2, (float*)d_out,
                                         coords, x_agg,
                                         (float*)d_out + (size_t)N * HH, N);
}

// Round 11
// 705.158 us; speedup vs baseline: 1.1118x; 1.1118x over previous
//
#include <hip/hip_runtime.h>
#include <math.h>

#define HH 128
#define HP 64   // u32 pairs per 128-feature row

typedef __attribute__((ext_vector_type(8))) short short8;
typedef __attribute__((ext_vector_type(4))) float float4v;
typedef __attribute__((ext_vector_type(4))) unsigned uint4v;

// ---------- helpers ----------
__device__ __forceinline__ float blo(unsigned w){ return __uint_as_float(w << 16); }
__device__ __forceinline__ float bhi(unsigned w){ return __uint_as_float(w & 0xffff0000u); }
__device__ __forceinline__ unsigned short f2b(float x){
  unsigned u = __float_as_uint(x);
  u += 0x7fffu + ((u >> 16) & 1u);           // RNE to bf16
  return (unsigned short)(u >> 16);
}
__device__ __forceinline__ unsigned pack2(float a, float b){
  return (unsigned)f2b(a) | ((unsigned)f2b(b) << 16);
}
__device__ __forceinline__ float silu_f(float x){ return x / (1.f + __expf(-x)); }

// LDS-only barrier (proven neutral vs __syncthreads, kept from v8)
__device__ __forceinline__ void bar_lds()
{
  __builtin_amdgcn_sched_barrier(0);
  asm volatile("s_waitcnt lgkmcnt(0)" ::: "memory");
  __builtin_amdgcn_s_barrier();
  asm volatile("" ::: "memory");
  __builtin_amdgcn_sched_barrier(0);
}

// ---------- 1) fused MFMA precompute ----------
// Output layout of A/B rows is PERMUTED for the edge kernel's dwordx4 gathers:
// pair index jp' = (n>>6)*32 + ((n&15)>>1)*4 + ((n>>4)&3)   [n = feature 0..127]
__global__ __launch_bounds__(256, 2) void precompute_mfma_kernel(
    const float* __restrict__ h,
    const float* __restrict__ We1, const float* __restrict__ be1,
    const float* __restrict__ Wc1, const float* __restrict__ bc1,
    unsigned* __restrict__ A1, unsigned* __restrict__ B1,
    unsigned* __restrict__ Ac, unsigned* __restrict__ Bc, int N)
{
  __shared__ unsigned short hs[2][16 * 136];  // 8.7 KB, stride 136

  const int t = threadIdx.x;
  const int lane = t & 63;
  const int w = t >> 6;
  const int col = lane & 15;
  const int quad = lane >> 4;

  const float* Wsel = (w < 2) ? We1 : Wc1;
  const int kb = (w & 1) * 128;               // row base within weight
  unsigned* outp = (w == 0) ? A1 : (w == 1) ? B1 : (w == 2) ? Ac : Bc;
  const float* biasp = (w == 0) ? be1 : (w == 2) ? bc1 : nullptr;

  uint4v wf[8][4];
  #pragma unroll
  for (int nt = 0; nt < 8; ++nt) {
    const int cn = nt * 16 + col;
    #pragma unroll
    for (int ks = 0; ks < 4; ++ks) {
      unsigned u[4];
      #pragma unroll
      for (int i = 0; i < 4; ++i) {
        const int k0 = kb + ks * 32 + quad * 8 + 2 * i;
        u[i] = pack2(Wsel[(size_t)k0 * 128 + cn], Wsel[(size_t)(k0 + 1) * 128 + cn]);
      }
      wf[nt][ks] = (uint4v){u[0], u[1], u[2], u[3]};
    }
  }
  float bias[8];
  #pragma unroll
  for (int nt = 0; nt < 8; ++nt) bias[nt] = biasp ? biasp[nt * 16 + col] : 0.f;

  const int ntiles = (N + 15) >> 4;
  auto stage = [&](int tl, int b) {
    const int n0s = tl * 16;
    for (int idx = t; idx < 16 * 64; idx += 256) {
      const int row = idx >> 6, jp = idx & 63;
      const int n = min(n0s + row, N - 1);
      float2 hv = ((const float2*)h)[(size_t)n * 64 + jp];
      ((unsigned*)&hs[b][row * 136])[jp] = pack2(hv.x, hv.y);
    }
  };

  int tile = blockIdx.x;
  if (tile < ntiles) stage(tile, 0);
  int buf = 0;
  for (; tile < ntiles; tile += gridDim.x, buf ^= 1) {
    __syncthreads();
    if (tile + (int)gridDim.x < ntiles) stage(tile + gridDim.x, buf ^ 1);

    float4v acc[8] = {{0,0,0,0},{0,0,0,0},{0,0,0,0},{0,0,0,0},
                      {0,0,0,0},{0,0,0,0},{0,0,0,0},{0,0,0,0}};
    #pragma unroll
    for (int ks = 0; ks < 4; ++ks) {
      short8 af = __builtin_bit_cast(short8,
          *(const uint4v*)&hs[buf][col * 136 + ks * 32 + quad * 8]);
      #pragma unroll
      for (int nt = 0; nt < 8; ++nt)
        acc[nt] = __builtin_amdgcn_mfma_f32_16x16x32_bf16(
            af, __builtin_bit_cast(short8, wf[nt][ks]), acc[nt], 0, 0, 0);
    }
    const int n0 = tile * 16;
    #pragma unroll
    for (int nt = 0; nt < 8; ++nt) {
      #pragma unroll
      for (int r = 0; r < 4; ++r) {
        float v = acc[nt][r] + bias[nt];
        float o = __shfl_xor(v, 1, 64);       // neighbor col's value
        const int node = n0 + quad * 4 + r;
        if (!(lane & 1) && node < N)
          outp[(size_t)node * HP + (nt >> 2) * 32 + ((col >> 1) << 2) + (nt & 3)]
              = pack2(v, o);
      }
    }
  }
}

// ---------- 2) dual-mode MFMA edge kernel ----------
// v9 = v8 per-block code EXACTLY, but both edge MLP (mode 0 -> h_agg) and coord
//      MLP (mode 1 -> x_agg) run in ONE dispatch, selected by blockIdx parity.
//      Each CU hosts ~1.5 blocks of each mode -> one mode's latency stalls
//      overlap the other's compute. Per-block envelope (3/CU, 32-edge tiles,
//      W2Ts in LDS, triple-buffered staging, 1-tile-ahead gathers) unchanged.
__global__ __launch_bounds__(256, 3) void edge_dual_kernel(
    const unsigned* __restrict__ A0, const unsigned* __restrict__ B0,
    const unsigned* __restrict__ A1p, const unsigned* __restrict__ B1p,
    const float* __restrict__ We1, const float* __restrict__ Wc1,  // tails rows 256..275
    const float* __restrict__ We2, const float* __restrict__ Wc2,
    const float* __restrict__ be2, const float* __restrict__ bc2,
    const float* __restrict__ Wa,  const float* __restrict__ Wc3,
    const float* __restrict__ ba,
    const int* __restrict__ src, const int* __restrict__ dst,
    const float* __restrict__ coords, const float* __restrict__ afeat,
    float* __restrict__ h_agg, float* __restrict__ x_agg, int E)
{
  __shared__ unsigned short W2Ts[128 * 136];  // 34 KB bf16, n-major
  __shared__ unsigned short mhl16[32 * 136];  // 8.7 KB bf16: mh[e][k]
  __shared__ unsigned short tailsA[3][32 * 40]; // 7.5 KB A-frags, k>=20 zero pad
  __shared__ float    dif[3][32 * 4];         // dx,dy,dz,rad
  __shared__ int      sl[3][32], dl[3][32];
  __shared__ float    p_lds[4][16];

  const int t = threadIdx.x;
  const int lane = t & 63;
  const int w = t >> 6;
  const int mtile = w >> 1;                   // 0/1 (16-edge half)
  const int nhalf = w & 1;                    // 0/1 (64-col half)
  const int col = lane & 15;
  const int quad = lane >> 4;

  // ---- mode selection by block parity (wave-uniform) ----
  const int  mode  = blockIdx.x & 1;          // 0: edge MLP, 1: coord MLP
  const int  bid   = blockIdx.x >> 1;
  const int  gs    = gridDim.x >> 1;          // per-mode grid stride
  const unsigned* Apart = mode ? A1p : A0;
  const unsigned* Bpart = mode ? B1p : B0;
  const float* W1 = mode ? Wc1 : We1;
  const float* W2 = mode ? Wc2 : We2;
  const float* b2 = mode ? bc2 : be2;
  const float* Wv = mode ? Wc3 : Wa;
  float* out_agg  = mode ? x_agg : h_agg;
  const float bav = mode ? 0.f : ba[0];

  for (int i = t; i < 128 * 128; i += 256) {
    int k = i >> 7, n = i & 127;
    W2Ts[n * 136 + k] = f2b(W2[i]);
  }
  for (int i = t; i < 3 * 32 * 20; i += 256) ((unsigned*)tailsA)[i] = 0u;

  uint4v wtf[4];
  #pragma unroll
  for (int nt = 0; nt < 4; ++nt) {
    const int n = nhalf * 64 + nt * 16 + col;
    unsigned u[4];
    #pragma unroll
    for (int i = 0; i < 4; ++i) {
      const int k0 = quad * 8 + 2 * i;
      float a = (k0     < 20) ? W1[(size_t)(256 + k0    ) * 128 + n] : 0.f;
      float b = (k0 + 1 < 20) ? W1[(size_t)(256 + k0 + 1) * 128 + n] : 0.f;
      u[i] = pack2(a, b);
    }
    wtf[nt] = (uint4v){u[0], u[1], u[2], u[3]};
  }
  float b2reg[4], wvreg[4];
  #pragma unroll
  for (int nt = 0; nt < 4; ++nt) {
    const int n = (nhalf * 4 + nt) * 16 + col;
    b2reg[nt] = b2[n];
    wvreg[nt] = Wv[n];
  }

  // ---- stage per-edge scalars + tail A-frag into buffer b ----
  auto stage = [&](int tl, int b) {
    const int e0s = tl * 32;
    if (t < 32) {
      int eg = e0s + t;
      int s = 0, d = 0;
      if (eg < E) { s = src[eg]; d = dst[eg]; }
      sl[b][t] = s; dl[b][t] = d;
      float dx = coords[s*3+0] - coords[d*3+0];
      float dy = coords[s*3+1] - coords[d*3+1];
      float dz = coords[s*3+2] - coords[d*3+2];
      float rad = sqrtf(dx*dx + dy*dy + dz*dz);
      dif[b][t*4+0] = dx; dif[b][t*4+1] = dy;
      dif[b][t*4+2] = dz; dif[b][t*4+3] = rad;
      unsigned* ta = (unsigned*)&tailsA[b][t * 40];
      ta[0] = pack2(rad, fabsf(dx));
      ta[1] = pack2(fabsf(dy), fabsf(dz));
    }
    if (t < 128) {                            // afeat: 32 edges x 4 float4
      int e = t >> 2, q4 = t & 3;
      int eg = e0s + e;
      float4 v = make_float4(0.f, 0.f, 0.f, 0.f);
      if (eg < E) v = ((const float4*)afeat)[(size_t)eg * 4 + q4];
      unsigned* d4 = (unsigned*)&tailsA[b][e * 40 + 4 + q4 * 4];
      d4[0] = pack2(v.x, v.y);
      d4[1] = pack2(v.z, v.w);
    }
  };

  const int ntiles = (E + 31) >> 5;
  const int T0 = bid;
  if (T0 < ntiles)      stage(T0, 0);
  if (T0 + gs < ntiles) stage(T0 + gs, 1);
  __syncthreads();                            // W2Ts + pads + stage(0,1) visible (full sync, once)

  // ---- pipelined gathers: dwordx4 per (edge r, A/B) thanks to permuted layout ----
  uint4v wa4[4], wb4[4];
  const int jb4 = nhalf * 32 + ((col >> 1) << 2);
  auto issueG = [&](int b) {
    #pragma unroll
    for (int r = 0; r < 4; ++r) {
      const int e = mtile * 16 + quad * 4 + r;
      wa4[r] = *(const uint4v*)(Apart + (size_t)sl[b][e] * HP + jb4);
      wb4[r] = *(const uint4v*)(Bpart + (size_t)dl[b][e] * HP + jb4);
    }
  };
  if (T0 < ntiles) issueG(0);

  int buf = 0;
  for (int tile = T0; tile < ntiles; tile += gs, buf = (buf == 2) ? 0 : buf + 1) {
    const int e0 = tile * 32;

    __builtin_amdgcn_s_setprio(1);            // compute-dense region begins

    // ---- tail MFMA: acct[nt][r] = tails(e_r) . W1tail[:, n] ----
    float4v acct[4] = {{0,0,0,0},{0,0,0,0},{0,0,0,0},{0,0,0,0}};
    {
      const unsigned short* ap = &tailsA[buf][(mtile * 16 + col) * 40 + quad * 8];
      short8 af = __builtin_bit_cast(short8, *(const uint4v*)ap);
      #pragma unroll
      for (int nt = 0; nt < 4; ++nt)
        acct[nt] = __builtin_amdgcn_mfma_f32_16x16x32_bf16(
            af, __builtin_bit_cast(short8, wtf[nt]), acct[nt], 0, 0, 0);
    }

    // ---- phase A: mh = silu(A[src] + B[dst] + tail) -> mhl16 ----
    const bool hiSel = (col & 1);
    #pragma unroll
    for (int r = 0; r < 4; ++r) {
      const int er_ = mtile * 16 + quad * 4 + r;
      #pragma unroll
      for (int nt = 0; nt < 4; ++nt) {
        unsigned ua = wa4[r][nt], ub = wb4[r][nt];
        float va = hiSel ? bhi(ua) : blo(ua);
        float vb = hiSel ? bhi(ub) : blo(ub);
        float v = va + vb + acct[nt][r];
        mhl16[er_ * 136 + nhalf * 64 + nt * 16 + col] = f2b(silu_f(v));
      }
    }
    bar_lds();                                // B1: mhl published; scatter(t-1) done -> buf reuse safe

    // ---- stage tile t+2 FIRST, THEN issue t+1 gathers (vmcnt oldest-first) ----
    if (tile + 2 * gs < ntiles) stage(tile + 2 * gs, (buf == 0) ? 2 : buf - 1);
    if (tile + gs < ntiles) issueG((buf == 2) ? 0 : buf + 1);

    // ---- phase B: layer 2 via MFMA ----
    float4v acc[4] = {{0,0,0,0},{0,0,0,0},{0,0,0,0},{0,0,0,0}};
    {
      const unsigned short* abase = &mhl16[(mtile * 16 + col) * 136 + quad * 8];
      #pragma unroll
      for (int ks = 0; ks < 4; ++ks) {
        short8 af = __builtin_bit_cast(short8, *(const uint4v*)(abase + ks * 32));
        #pragma unroll
        for (int nt = 0; nt < 4; ++nt) {
          const unsigned short* bp =
              &W2Ts[((nhalf * 4 + nt) * 16 + col) * 136 + ks * 32 + quad * 8];
          short8 bf = __builtin_bit_cast(short8, *(const uint4v*)bp);
          acc[nt] = __builtin_amdgcn_mfma_f32_16x16x32_bf16(af, bf, acc[nt], 0, 0, 0);
        }
      }
    }

    // ---- epilogue: bias + silu + head dot, cross-wave reduce ----
    float p[4] = {0.f, 0.f, 0.f, 0.f};
    #pragma unroll
    for (int nt = 0; nt < 4; ++nt)
      #pragma unroll
      for (int r = 0; r < 4; ++r) {
        float v = silu_f(acc[nt][r] + b2reg[nt]);
        acc[nt][r] = v;
        p[r] += v * wvreg[nt];
      }
    #pragma unroll
    for (int r = 0; r < 4; ++r) {
      #pragma unroll
      for (int off = 1; off < 16; off <<= 1) p[r] += __shfl_xor(p[r], off, 64);
    }
    if (col == 0) {
      #pragma unroll
      for (int r = 0; r < 4; ++r) p_lds[w][quad * 4 + r] = p[r];
    }
    __builtin_amdgcn_s_setprio(0);            // compute-dense region ends
    bar_lds();                                // B2: p_lds + stage(t+2) published

    // ---- scatter (mode branch is wave-uniform) ----
    #pragma unroll
    for (int r = 0; r < 4; ++r) {
      const int le = quad * 4 + r;
      const int ei = mtile * 16 + le;
      const int eg = e0 + ei;
      const float pfull = p_lds[w][le] + p_lds[w ^ 1][le];
      if (mode == 0) {
        if (eg < E) {
          float att = 1.f / (1.f + __expf(-(pfull + bav)));
          int d = dl[buf][ei];
          #pragma unroll
          for (int nt = 0; nt < 4; ++nt) {
            int n = (nhalf * 4 + nt) * 16 + col;
            unsafeAtomicAdd(&out_agg[(size_t)d * HH + n], att * acc[nt][r]);
          }
        }
      } else {
        if (nhalf == 0 && eg < E && col < 3) {
          float rad = dif[buf][ei * 4 + 3];
          float fac = pfull / (rad + 1.f);
          unsafeAtomicAdd(&out_agg[(size_t)dl[buf][ei] * 3 + col],
                          fac * dif[buf][ei * 4 + col]);
        }
      }
    }
    // no trailing barrier: B1 of the next iteration is the rendezvous
  }
}

// ---------- 3) node MLP layer 1 via MFMA ----------
__global__ __launch_bounds__(256, 4) void node_l1_mfma(
    const float* __restrict__ h, const float* __restrict__ h_agg,
    const float* __restrict__ Wn1, const float* __restrict__ bn1,
    unsigned* __restrict__ g, int N)
{
  __shared__ unsigned short xs[2][16 * 264];

  const int t = threadIdx.x;
  const int lane = t & 63;
  const int w = t >> 6;
  const int col = lane & 15;
  const int quad = lane >> 4;
  const int wbase = w * 32;

  uint4v wf[2][8];
  #pragma unroll
  for (int nt = 0; nt < 2; ++nt) {
    const int cn = wbase + nt * 16 + col;
    #pragma unroll
    for (int ks = 0; ks < 8; ++ks) {
      unsigned u[4];
      #pragma unroll
      for (int i = 0; i < 4; ++i) {
        const int k0 = ks * 32 + quad * 8 + 2 * i;
        u[i] = pack2(Wn1[(size_t)k0 * 128 + cn], Wn1[(size_t)(k0 + 1) * 128 + cn]);
      }
      wf[nt][ks] = (uint4v){u[0], u[1], u[2], u[3]};
    }
  }
  float bias[2] = { bn1[wbase + col], bn1[wbase + 16 + col] };

  const int ntiles = (N + 15) >> 4;
  auto stage = [&](int tl, int b) {
    const int n0s = tl * 16;
    for (int idx = t; idx < 16 * 128; idx += 256) {
      const int row = idx >> 7, jp = idx & 127;
      const int n = min(n0s + row, N - 1);
      float2 v = (jp < 64) ? ((const float2*)h)[(size_t)n * 64 + jp]
                           : ((const float2*)h_agg)[(size_t)n * 64 + (jp - 64)];
      ((unsigned*)&xs[b][row * 264])[jp] = pack2(v.x, v.y);
    }
  };

  int tile = blockIdx.x;
  if (tile < ntiles) stage(tile, 0);
  int buf = 0;
  for (; tile < ntiles; tile += gridDim.x, buf ^= 1) {
    __syncthreads();
    if (tile + (int)gridDim.x < ntiles) stage(tile + gridDim.x, buf ^ 1);

    float4v acc[2] = {{0,0,0,0},{0,0,0,0}};
    #pragma unroll
    for (int ks = 0; ks < 8; ++ks) {
      short8 af = __builtin_bit_cast(short8,
          *(const uint4v*)&xs[buf][col * 264 + ks * 32 + quad * 8]);
      acc[0] = __builtin_amdgcn_mfma_f32_16x16x32_bf16(
          af, __builtin_bit_cast(short8, wf[0][ks]), acc[0], 0, 0, 0);
      acc[1] = __builtin_amdgcn_mfma_f32_16x16x32_bf16(
          af, __builtin_bit_cast(short8, wf[1][ks]), acc[1], 0, 0, 0);
    }
    const int n0 = tile * 16;
    #pragma unroll
    for (int nt = 0; nt < 2; ++nt) {
      #pragma unroll
      for (int r = 0; r < 4; ++r) {
        float v = silu_f(acc[nt][r] + bias[nt]);
        float o = __shfl_xor(v, 1, 64);
        const int node = n0 + quad * 4 + r;
        if (!(lane & 1) && node < N)
          g[(size_t)node * HP + ((wbase + nt * 16 + col) >> 1)] = pack2(v, o);
      }
    }
  }
}

// ---------- 4) node MLP layer 2 via MFMA (+ fused coords_out epilogue) ----------
__global__ __launch_bounds__(256, 4) void node_l2_mfma(
    const unsigned* __restrict__ g, const float* __restrict__ h,
    const float* __restrict__ Wn2, const float* __restrict__ bn2,
    float* __restrict__ hout,
    const float* __restrict__ coords, const float* __restrict__ x_agg,
    float* __restrict__ cout, int N)
{
  const int t = threadIdx.x;
  const int lane = t & 63;
  const int w = t >> 6;
  const int col = lane & 15;
  const int quad = lane >> 4;
  const int wbase = w * 32;

  uint4v wf[2][4];
  #pragma unroll
  for (int nt = 0; nt < 2; ++nt) {
    const int cn = wbase + nt * 16 + col;
    #pragma unroll
    for (int ks = 0; ks < 4; ++ks) {
      unsigned u[4];
      #pragma unroll
      for (int i = 0; i < 4; ++i) {
        const int k0 = ks * 32 + quad * 8 + 2 * i;
        u[i] = pack2(Wn2[(size_t)k0 * 128 + cn], Wn2[(size_t)(k0 + 1) * 128 + cn]);
      }
      wf[nt][ks] = (uint4v){u[0], u[1], u[2], u[3]};
    }
  }
  float bias[2] = { bn2[wbase + col], bn2[wbase + 16 + col] };

  const int ntiles = (N + 15) >> 4;
  for (int tile = blockIdx.x; tile < ntiles; tile += gridDim.x) {
    const int n0 = tile * 16;
    const int na = min(n0 + col, N - 1);

    float4v acc[2] = {{0,0,0,0},{0,0,0,0}};
    #pragma unroll
    for (int ks = 0; ks < 4; ++ks) {
      short8 af = __builtin_bit_cast(short8,
          *(const uint4v*)(g + (size_t)na * HP + ks * 16 + quad * 4));
      acc[0] = __builtin_amdgcn_mfma_f32_16x16x32_bf16(
          af, __builtin_bit_cast(short8, wf[0][ks]), acc[0], 0, 0, 0);
      acc[1] = __builtin_amdgcn_mfma_f32_16x16x32_bf16(
          af, __builtin_bit_cast(short8, wf[1][ks]), acc[1], 0, 0, 0);
    }
    #pragma unroll
    for (int nt = 0; nt < 2; ++nt) {
      const int cn = wbase + nt * 16 + col;
      #pragma unroll
      for (int r = 0; r < 4; ++r) {
        const int node = n0 + quad * 4 + r;
        if (node < N) {
          float v = acc[nt][r] + bias[nt] + h[(size_t)node * HH + cn];
          hout[(size_t)node * HH + cn] = v;
        }
      }
    }
  }

  // fused coords_out: cout = coords + x_agg (independent streaming epilogue)
  const int n3 = N * 3;
  for (int i = blockIdx.x * blockDim.x + threadIdx.x; i < n3;
       i += gridDim.x * blockDim.x)
    cout[i] = coords[i] + x_agg[i];
}

extern "C" void kernel_launch(void* const* d_in, const int* in_sizes, int n_in,
                              void* d_out, int out_size, void* d_ws, size_t ws_size,
                              hipStream_t stream)
{
  const float* h      = (const float*)d_in[0];
  const float* coords = (const float*)d_in[1];
  const float* afeat  = (const float*)d_in[2];
  const int*   src    = (const int*)d_in[3];
  const int*   dst    = (const int*)d_in[4];
  const float* We1 = (const float*)d_in[5];
  const float* be1 = (const float*)d_in[6];
  const float* We2 = (const float*)d_in[7];
  const float* be2 = (const float*)d_in[8];
  const float* Wa  = (const float*)d_in[9];
  const float* ba  = (const float*)d_in[10];
  const float* Wn1 = (const float*)d_in[11];
  const float* bn1 = (const float*)d_in[12];
  const float* Wn2 = (const float*)d_in[13];
  const float* bn2 = (const float*)d_in[14];
  const float* Wc1 = (const float*)d_in[15];
  const float* bc1 = (const float*)d_in[16];
  const float* Wc2 = (const float*)d_in[17];
  const float* bc2 = (const float*)d_in[18];
  const float* Wc3 = (const float*)d_in[19];

  const int E = in_sizes[3];
  const int N = in_sizes[0] / HH;

  unsigned* A1 = (unsigned*)d_ws;
  unsigned* B1 = A1 + (size_t)N * HP;
  unsigned* Ac = B1 + (size_t)N * HP;
  unsigned* Bc = Ac + (size_t)N * HP;
  float* h_agg = (float*)(Bc + (size_t)N * HP);
  float* x_agg = h_agg + (size_t)N * HH;
  unsigned* gbuf = A1;                        // reuse after edge kernel finishes

  hipMemsetAsync(h_agg, 0, ((size_t)N * HH + (size_t)N * 3) * sizeof(float), stream);

  precompute_mfma_kernel<<<512, 256, 0, stream>>>(h, We1, be1, Wc1, bc1,
                                                  A1, B1, Ac, Bc, N);

  // one dispatch, both modes interleaved by block parity (768 blocks per mode)
  edge_dual_kernel<<<1536, 256, 0, stream>>>(A1, B1, Ac, Bc,
                                             We1, Wc1, We2, Wc2, be2, bc2,
                                             Wa, Wc3, ba,
                                             src, dst, coords, afeat,
                                             h_agg, x_agg, E);

  node_l1_mfma<<<512, 256, 0, stream>>>(h, h_agg, Wn1, bn1, gbuf, N);
  node_l2_mfma<<<1024, 256, 0, stream>>>(gbuf, h, Wn2, bn2, (float*)d_out,
                                         coords, x_agg,
                                         (float*)d_out + (size_t)N * HH, N);
}